// Round 5
// baseline (566.720 us; speedup 1.0000x reference)
//
#include <hip/hip_runtime.h>
#include <hip/hip_cooperative_groups.h>
namespace cg = cooperative_groups;

constexpr int NB = 8, NA = 64, NT = 12, NH = 128, NTY = 8, NSC = 32, NAG = 16;

struct Params {
    const float *traj, *ntraj, *ty, *sd, *adata, *rel;
    const float *W_in, *b_in, *W_nt, *b_nt, *W_ag, *b_ag, *W_sc, *b_sc;
    const float *W_ein, *b_ein, *W_ety, *b_ety;
    const float *W_edge, *b_edge, *W_self, *b_self, *W_e2n, *b_e2n;
    const float *W_ih, *W_hh, *b_ih, *b_hh, *W_pred, *b_pred;
    float *h0, *h1, *R;
    float *Wty, *Wsc, *Wag, *Wcomb, *vbase, *vag, *vbe, *sesty, *Xs, *out;
};

// ---- Fold small encoders into W_ih blocks (K=128 each) ----
// x layout for W_ih rows: [coord 0:128 | type 128:256 | node 256:384 | scene 384:512 | agent 512:640]
__global__ __launch_bounds__(512) void k_fold(Params p) {
    const int blk = blockIdx.x, c = threadIdx.x;
    __shared__ float lrow[NH];
    __shared__ float b1[NH], b2[NH], b3[NH], b4[NH];
    if (blk < 184) {
        const float* src; int ihoff, row; float* dst;
        if (blk < 8)       { row = blk;      src = p.W_nt  + row * NH; ihoff = 128; dst = p.Wty; }
        else if (blk < 40) { row = blk - 8;  src = p.W_sc  + row * NH; ihoff = 384; dst = p.Wsc; }
        else if (blk < 56) { row = blk - 40; src = p.W_ag  + row * NH; ihoff = 512; dst = p.Wag; }
        else               { row = blk - 56; src = p.W_e2n + row * NH; ihoff = 256; dst = p.Wcomb; }
        if (c < NH) lrow[c] = src[c];
        __syncthreads();
        float acc = 0.f;
        for (int k = 0; k < NH; ++k) acc += lrow[k] * p.W_ih[(ihoff + k) * 512 + c];
        dst[row * 512 + c] = acc;
    } else {
        if (c < NH) { b1[c] = p.b_nt[c]; b2[c] = p.b_sc[c]; b3[c] = p.b_ag[c]; b4[c] = p.b_e2n[c]; }
        __syncthreads();
        float vb = p.b_ih[c] + p.b_hh[c], va = 0.f, ve = 0.f;
        for (int k = 0; k < NH; ++k) {
            vb += b1[k] * p.W_ih[(128 + k) * 512 + c] + b2[k] * p.W_ih[(384 + k) * 512 + c];
            va += b3[k] * p.W_ih[(512 + k) * 512 + c];
            ve += b4[k] * p.W_ih[(256 + k) * 512 + c];
        }
        p.vbase[c] = vb; p.vag[c] = va; p.vbe[c] = ve;
    }
}

// ---- R0 closed form + sesty (t-invariant ty@W_self3 + b_self) ----
__global__ void k_r0(Params p) {
    const int row = blockIdx.x, n = threadIdx.x;
    const int b = row / NA, i = row % NA;
    __shared__ float lf[NA][6];
    __shared__ float lt[NA][NTY];
    __shared__ float sumf[6], sumt[NTY];
    if (threadIdx.x < NA) {
        int j = threadIdx.x, rj = b * NA + j;
        for (int k = 0; k < 3; ++k) {
            lf[j][k]     = p.ntraj[(rj * NT + 0) * 3 + k];
            lf[j][3 + k] = p.traj [(rj * NT + 0) * 3 + k];
        }
        for (int k = 0; k < NTY; ++k) lt[j][k] = p.ty[rj * NTY + k];
    }
    __syncthreads();
    if (threadIdx.x < 6) {
        float s = 0.f; for (int j = 0; j < NA; ++j) s += lf[j][threadIdx.x];
        sumf[threadIdx.x] = s;
    } else if (threadIdx.x < 6 + NTY) {
        int k = threadIdx.x - 6; float s = 0.f;
        for (int j = 0; j < NA; ++j) s += lt[j][k];
        sumt[k] = s;
    }
    __syncthreads();
    float acc_i = p.b_ein[n] + p.b_ety[n];
    for (int k = 0; k < 6; ++k)   acc_i += lf[i][k] * p.W_ein[k * NH + n];
    for (int k = 0; k < NTY; ++k) acc_i += lt[i][k] * (p.W_ein[(12 + k) * NH + n] + p.W_ety[k * NH + n]);
    float acc_j = 0.f;
    for (int k = 0; k < 6; ++k)   acc_j += sumf[k] * p.W_ein[(6 + k) * NH + n];
    for (int k = 0; k < NTY; ++k) acc_j += sumt[k] * (p.W_ein[(20 + k) * NH + n] + p.W_ety[(NTY + k) * NH + n]);
    p.R[row * NH + n] = 64.f * acc_i + acc_j;
    float sv = p.b_self[n];
    for (int k = 0; k < NTY; ++k) sv += lt[i][k] * p.W_self[(2 * NH + k) * NH + n];
    p.sesty[row * NH + n] = sv;
}

// ---- X_static[(g,t), 512]; vbe folded in for t>0 ----
__global__ __launch_bounds__(512) void k_xstatic(Params p) {
    const int g = blockIdx.x, tid = threadIdx.x, b = g >> 6;
    __shared__ float coordL[NT][NH];
    __shared__ float sceneL[NT][NSC];
    __shared__ float agentL[NT][NAG];
    __shared__ float tyL[NTY];
    const float relv = p.rel[g];
    for (int idx = tid; idx < NT * NH; idx += 512) {
        int r = idx >> 7, k = idx & 127;
        float acc = p.b_in[k];
        const float* nt = p.ntraj + (g * NT + r) * 3;
        const float* tr = p.traj  + (g * NT + r) * 3;
        for (int j = 0; j < 3; ++j) acc += nt[j] * p.W_in[j * NH + k] + tr[j] * p.W_in[(3 + j) * NH + k];
        coordL[r][k] = fmaxf(acc, 0.f);
    }
    for (int i = tid; i < NT * NSC; i += 512) { int r = i >> 5, k = i & 31; sceneL[r][k] = p.sd[(b * NT + r) * NSC + k]; }
    for (int i = tid; i < NT * NAG; i += 512) { int r = i >> 4, k = i & 15; agentL[r][k] = p.adata[(g * NT + r) * NAG + k] * relv; }
    if (tid < NTY) tyL[tid] = p.ty[g * NTY + tid];
    __syncthreads();
    const int c = tid;
    float base = p.vbase[c] + relv * p.vag[c];
    for (int i = 0; i < NTY; ++i) base += tyL[i] * p.Wty[i * 512 + c];
    const float vbeL = p.vbe[c];
    float acc[NT];
#pragma unroll
    for (int r = 0; r < NT; ++r) acc[r] = base + (r > 0 ? vbeL : 0.f);
    for (int k = 0; k < NH; ++k) { float w = p.W_ih[k * 512 + c];
#pragma unroll
        for (int r = 0; r < NT; ++r) acc[r] += coordL[r][k] * w; }
    for (int k = 0; k < NSC; ++k) { float w = p.Wsc[k * 512 + c];
#pragma unroll
        for (int r = 0; r < NT; ++r) acc[r] += sceneL[r][k] * w; }
    for (int k = 0; k < NAG; ++k) { float w = p.Wag[k * 512 + c];
#pragma unroll
        for (int r = 0; r < NT; ++r) acc[r] += agentL[r][k] * w; }
#pragma unroll
    for (int r = 0; r < NT; ++r) p.Xs[((size_t)(g * NT + r)) * 512 + c] = acc[r];
}

// ---- Persistent recurrence: 256 blocks x 512 threads, 2 rows/block, 12 steps ----
// Block-local state (R, se, c, h) lives in LDS across all steps; only h goes
// to global (double-buffered) for the cross-block batch h-sum. One grid.sync
// per step.
__global__ __launch_bounds__(512) void k_persist(Params p) {
    const int tid = threadIdx.x;
    const int r0 = blockIdx.x * 2;
    const int b = r0 >> 6;
    const int n = tid & 127;
    const int sel = tid >> 7;        // 0..3
    const int r = sel & 1, sg = sel >> 1;

    __shared__ float lh[2][NH], lR[2][NH], lse[2][NH], lc[2][NH], lsty[2][NH];
    __shared__ float psum[4][NH];
    __shared__ float hsumL[NH], shw2[NH];
    __shared__ float lA[2][NH], lS[2][NH];
    __shared__ float lagg[2][NH];
    __shared__ float lg[2][512];

    if (tid < 256) {
        int rr = tid >> 7, k = tid & 127;
        lh[rr][k] = 0.f; lse[rr][k] = 0.f; lc[rr][k] = 0.f;
        lR[rr][k]   = p.R[(r0 + rr) * NH + k];
        lsty[rr][k] = p.sesty[(r0 + rr) * NH + k];
    }
    const float bedge64 = 64.f * p.b_edge[n];
    cg::grid_group grid = cg::this_grid();
    __syncthreads();

#pragma unroll 1
    for (int t = 0; t < NT; ++t) {
        // hsum + shw2 (cross-block input: h from step t-1)
        if (t > 0) {
            const float* __restrict__ hprev = ((t - 1) & 1) ? p.h1 : p.h0;
            {
                float s = 0.f;
                const float* hb = hprev + (b * NA + sel * 16) * NH + n;
#pragma unroll
                for (int j = 0; j < 16; ++j) s += hb[j * NH];
                psum[sel][n] = s;
            }
            __syncthreads();
            if (tid < NH) hsumL[tid] = psum[0][tid] + psum[1][tid] + psum[2][tid] + psum[3][tid];
            __syncthreads();
            {
                float s = 0.f;
                const float* w2 = p.W_edge + NH * NH + n;
#pragma unroll 8
                for (int k = 32 * sel; k < 32 * sel + 32; ++k) s += hsumL[k] * w2[k * NH];
                psum[sel][n] = s;
            }
            __syncthreads();
            if (tid < NH) shw2[tid] = psum[0][tid] + psum[1][tid] + psum[2][tid] + psum[3][tid];
        } else {
            if (tid < NH) shw2[tid] = 0.f;
        }
        __syncthreads();

        // Stage A: group (r, sg): sg0 -> R path (w1, w3); sg1 -> se path (ws1, ws2).
        if (sg == 0) {
            float a1 = 0.f, a3 = 0.f;
            const float* w1 = p.W_edge + n;
            const float* w3 = p.W_edge + 2 * NH * NH + n;
#pragma unroll 8
            for (int k = 0; k < NH; ++k) {
                a1 += lh[r][k] * w1[k * NH];
                a3 += lR[r][k] * w3[k * NH];
            }
            lA[r][n] = 64.f * a1 + shw2[n] + a3 + bedge64;
        } else {
            float aS = 0.f;
            const float* ws1 = p.W_self + n;
            const float* ws2 = p.W_self + NH * NH + n;
#pragma unroll 8
            for (int k = 0; k < NH; ++k)
                aS += lh[r][k] * ws1[k * NH] + lse[r][k] * ws2[k * NH];
            lS[r][n] = aS + lsty[r][n];
        }
        __syncthreads();
        if (tid < 256) {
            int rr = tid >> 7, k = tid & 127;
            float Rn = lA[rr][k], Sn = lS[rr][k];
            lR[rr][k] = Rn; lse[rr][k] = Sn;
            lagg[rr][k] = Rn + Sn;
        }
        __syncthreads();

        // Stage C: gates; thread = col c (0..511) for both rows (weight reuse x2).
        {
            const int c = tid;
            float a0 = p.Xs[((size_t)r0 * NT + t) * 512 + c];
            float a1v = p.Xs[((size_t)(r0 + 1) * NT + t) * 512 + c];
            if (t > 0) {
                const float* wc = p.Wcomb + c;
                const float* wh = p.W_hh + c;
#pragma unroll 8
                for (int k = 0; k < NH; ++k) {
                    float w = wc[k * 512];
                    a0 += lagg[0][k] * w; a1v += lagg[1][k] * w;
                }
#pragma unroll 8
                for (int k = 0; k < NH; ++k) {
                    float w = wh[k * 512];
                    a0 += lh[0][k] * w; a1v += lh[1][k] * w;
                }
            }
            lg[0][c] = a0; lg[1][c] = a1v;
        }
        __syncthreads();

        // Stage D: LSTM elementwise; update local state; publish h row.
        {
            float* hw = (t & 1) ? p.h1 : p.h0;
            if (tid < 256) {
                int rr = tid >> 7, k = tid & 127;
                float gi = lg[rr][k], gf = lg[rr][NH + k], gg = lg[rr][2 * NH + k], go = lg[rr][3 * NH + k];
                float si = 1.f / (1.f + expf(-gi));
                float sf = 1.f / (1.f + expf(-gf));
                float so = 1.f / (1.f + expf(-go));
                float cn = sf * lc[rr][k] + si * tanhf(gg);
                float hn = so * tanhf(cn);
                lc[rr][k] = cn; lh[rr][k] = hn;
                hw[(r0 + rr) * NH + k] = hn;
            }
        }
        __syncthreads();

        // Out projection (split-K over sg): out[g,t,:] = relu(h_new @ W_pred + b_pred)
        {
            float s = 0.f;
            const float* wp = p.W_pred + n;
#pragma unroll 8
            for (int k = 64 * sg; k < 64 * sg + 64; ++k) s += lh[r][k] * wp[k * NH];
            psum[sel][n] = s;
        }
        __syncthreads();
        if (tid < 256) {
            int rr = tid >> 7, k = tid & 127;
            float v = psum[rr][k] + psum[rr + 2][k] + p.b_pred[k];
            p.out[((size_t)(r0 + rr) * NT + t) * NH + k] = fmaxf(v, 0.f);
        }
        grid.sync();
    }
}

extern "C" void kernel_launch(void* const* d_in, const int* in_sizes, int n_in,
                              void* d_out, int out_size, void* d_ws, size_t ws_size,
                              hipStream_t stream) {
    const float* const* in = (const float* const*)d_in;
    Params p;
    p.traj = in[0]; p.ntraj = in[1]; p.ty = in[2]; p.sd = in[3]; p.adata = in[4]; p.rel = in[5];
    p.W_in = in[6]; p.b_in = in[7]; p.W_nt = in[8]; p.b_nt = in[9];
    p.W_ag = in[10]; p.b_ag = in[11]; p.W_sc = in[12]; p.b_sc = in[13];
    p.W_ein = in[14]; p.b_ein = in[15]; p.W_ety = in[16]; p.b_ety = in[17];
    p.W_edge = in[18]; p.b_edge = in[19]; p.W_self = in[20]; p.b_self = in[21];
    p.W_e2n = in[22]; p.b_e2n = in[23];
    p.W_ih = in[24]; p.W_hh = in[25]; p.b_ih = in[26]; p.b_hh = in[27];
    p.W_pred = in[28]; p.b_pred = in[29];

    float* ws = (float*)d_ws;
    const size_t S = (size_t)NB * NA * NH;   // 65536
    p.h0 = ws;                // written by k_persist before first read
    p.h1 = ws + S;
    p.R  = ws + 2 * S;        // k_r0
    p.sesty = ws + 3 * S;     // k_r0
    float* w = ws + 4 * S;
    p.Wty   = w;              w += 8 * 512;
    p.Wsc   = w;              w += 32 * 512;
    p.Wag   = w;              w += 16 * 512;
    p.Wcomb = w;              w += 128 * 512;
    p.vbase = w;              w += 512;
    p.vag   = w;              w += 512;
    p.vbe   = w;              w += 512;
    p.Xs    = w;              w += (size_t)NB * NA * NT * 512;
    p.out = (float*)d_out;

    k_fold<<<185, 512, 0, stream>>>(p);
    k_r0<<<NB * NA, 128, 0, stream>>>(p);
    k_xstatic<<<NB * NA, 512, 0, stream>>>(p);

    void* args[] = { (void*)&p };
    hipLaunchCooperativeKernel((void*)k_persist, dim3(NB * NA / 2), dim3(512),
                               args, 0, stream);
}

// Round 6
// 192.650 us; speedup vs baseline: 2.9417x; 2.9417x over previous
//
#include <hip/hip_runtime.h>

constexpr int NB = 8, NA = 64, NT = 12, NH = 128, NTY = 8, NSC = 32, NAG = 16;

struct Params {
    const float *traj, *ntraj, *ty, *sd, *adata, *rel;
    const float *W_in, *b_in, *W_nt, *b_nt, *W_ag, *b_ag, *W_sc, *b_sc;
    const float *W_ein, *b_ein, *W_ety, *b_ety;
    const float *W_edge, *b_edge, *W_self, *b_self, *W_e2n, *b_e2n;
    const float *W_ih, *W_hh, *b_ih, *b_hh, *W_pred, *b_pred;
    float *h0, *h1, *c, *se, *R;
    float *Wty, *Wsc, *Wag, *Wcomb, *vbase, *vag, *vbe, *sesty, *Xs, *hall, *out;
};

// ---- Fold small encoders into W_ih blocks (K=128 each) ----
// x layout for W_ih rows: [coord 0:128 | type 128:256 | node 256:384 | scene 384:512 | agent 512:640]
__global__ __launch_bounds__(512) void k_fold(Params p) {
    const int blk = blockIdx.x, c = threadIdx.x;
    __shared__ float lrow[NH];
    __shared__ float b1[NH], b2[NH], b3[NH], b4[NH];
    if (blk < 184) {
        const float* src; int ihoff, row; float* dst;
        if (blk < 8)       { row = blk;      src = p.W_nt  + row * NH; ihoff = 128; dst = p.Wty; }
        else if (blk < 40) { row = blk - 8;  src = p.W_sc  + row * NH; ihoff = 384; dst = p.Wsc; }
        else if (blk < 56) { row = blk - 40; src = p.W_ag  + row * NH; ihoff = 512; dst = p.Wag; }
        else               { row = blk - 56; src = p.W_e2n + row * NH; ihoff = 256; dst = p.Wcomb; }
        if (c < NH) lrow[c] = src[c];
        __syncthreads();
        float acc = 0.f;
        for (int k = 0; k < NH; ++k) acc += lrow[k] * p.W_ih[(ihoff + k) * 512 + c];
        dst[row * 512 + c] = acc;
    } else {
        if (c < NH) { b1[c] = p.b_nt[c]; b2[c] = p.b_sc[c]; b3[c] = p.b_ag[c]; b4[c] = p.b_e2n[c]; }
        __syncthreads();
        float vb = p.b_ih[c] + p.b_hh[c], va = 0.f, ve = 0.f;
        for (int k = 0; k < NH; ++k) {
            vb += b1[k] * p.W_ih[(128 + k) * 512 + c] + b2[k] * p.W_ih[(384 + k) * 512 + c];
            va += b3[k] * p.W_ih[(512 + k) * 512 + c];
            ve += b4[k] * p.W_ih[(256 + k) * 512 + c];
        }
        p.vbase[c] = vb; p.vag[c] = va; p.vbe[c] = ve;
    }
}

// ---- R0 closed form + sesty (t-invariant ty@W_self3 + b_self) ----
__global__ void k_r0(Params p) {
    const int row = blockIdx.x, n = threadIdx.x;
    const int b = row / NA, i = row % NA;
    __shared__ float lf[NA][6];
    __shared__ float lt[NA][NTY];
    __shared__ float sumf[6], sumt[NTY];
    if (threadIdx.x < NA) {
        int j = threadIdx.x, rj = b * NA + j;
        for (int k = 0; k < 3; ++k) {
            lf[j][k]     = p.ntraj[(rj * NT + 0) * 3 + k];
            lf[j][3 + k] = p.traj [(rj * NT + 0) * 3 + k];
        }
        for (int k = 0; k < NTY; ++k) lt[j][k] = p.ty[rj * NTY + k];
    }
    __syncthreads();
    if (threadIdx.x < 6) {
        float s = 0.f; for (int j = 0; j < NA; ++j) s += lf[j][threadIdx.x];
        sumf[threadIdx.x] = s;
    } else if (threadIdx.x < 6 + NTY) {
        int k = threadIdx.x - 6; float s = 0.f;
        for (int j = 0; j < NA; ++j) s += lt[j][k];
        sumt[k] = s;
    }
    __syncthreads();
    float acc_i = p.b_ein[n] + p.b_ety[n];
    for (int k = 0; k < 6; ++k)   acc_i += lf[i][k] * p.W_ein[k * NH + n];
    for (int k = 0; k < NTY; ++k) acc_i += lt[i][k] * (p.W_ein[(12 + k) * NH + n] + p.W_ety[k * NH + n]);
    float acc_j = 0.f;
    for (int k = 0; k < 6; ++k)   acc_j += sumf[k] * p.W_ein[(6 + k) * NH + n];
    for (int k = 0; k < NTY; ++k) acc_j += sumt[k] * (p.W_ein[(20 + k) * NH + n] + p.W_ety[(NTY + k) * NH + n]);
    p.R[row * NH + n] = 64.f * acc_i + acc_j;
    float sv = p.b_self[n];
    for (int k = 0; k < NTY; ++k) sv += lt[i][k] * p.W_self[(2 * NH + k) * NH + n];
    p.sesty[row * NH + n] = sv;
}

// ---- X_static[(g,t), 512]; vbe folded in for t>0 ----
__global__ __launch_bounds__(512) void k_xstatic(Params p) {
    const int g = blockIdx.x, tid = threadIdx.x, b = g >> 6;
    __shared__ float coordL[NT][NH];
    __shared__ float sceneL[NT][NSC];
    __shared__ float agentL[NT][NAG];
    __shared__ float tyL[NTY];
    const float relv = p.rel[g];
    for (int idx = tid; idx < NT * NH; idx += 512) {
        int r = idx >> 7, k = idx & 127;
        float acc = p.b_in[k];
        const float* nt = p.ntraj + (g * NT + r) * 3;
        const float* tr = p.traj  + (g * NT + r) * 3;
        for (int j = 0; j < 3; ++j) acc += nt[j] * p.W_in[j * NH + k] + tr[j] * p.W_in[(3 + j) * NH + k];
        coordL[r][k] = fmaxf(acc, 0.f);
    }
    for (int i = tid; i < NT * NSC; i += 512) { int r = i >> 5, k = i & 31; sceneL[r][k] = p.sd[(b * NT + r) * NSC + k]; }
    for (int i = tid; i < NT * NAG; i += 512) { int r = i >> 4, k = i & 15; agentL[r][k] = p.adata[(g * NT + r) * NAG + k] * relv; }
    if (tid < NTY) tyL[tid] = p.ty[g * NTY + tid];
    __syncthreads();
    const int c = tid;
    float base = p.vbase[c] + relv * p.vag[c];
    for (int i = 0; i < NTY; ++i) base += tyL[i] * p.Wty[i * 512 + c];
    const float vbeL = p.vbe[c];
    float acc[NT];
#pragma unroll
    for (int r = 0; r < NT; ++r) acc[r] = base + (r > 0 ? vbeL : 0.f);
    for (int k = 0; k < NH; ++k) { float w = p.W_ih[k * 512 + c];
#pragma unroll
        for (int r = 0; r < NT; ++r) acc[r] += coordL[r][k] * w; }
    for (int k = 0; k < NSC; ++k) { float w = p.Wsc[k * 512 + c];
#pragma unroll
        for (int r = 0; r < NT; ++r) acc[r] += sceneL[r][k] * w; }
    for (int k = 0; k < NAG; ++k) { float w = p.Wag[k * 512 + c];
#pragma unroll
        for (int r = 0; r < NT; ++r) acc[r] += agentL[r][k] * w; }
#pragma unroll
    for (int r = 0; r < NT; ++r) p.Xs[((size_t)(g * NT + r)) * 512 + c] = acc[r];
}

// ---- One recurrence step: 2 rows/block, 256 blocks x 1024 threads ----
// 16 waves/CU; all K-loops split-K across thread groups for latency hiding.
__global__ __launch_bounds__(1024) void k_step(Params p, int t) {
    const int tid = threadIdx.x;
    const int r0 = blockIdx.x * 2;
    const int b = r0 >> 6;
    const int n = tid & 127;
    const int g8 = tid >> 7;                 // 0..7
    const float* __restrict__ hcur = (t & 1) ? p.h1 : p.h0;
    float* hnxt = (t & 1) ? p.h0 : p.h1;

    __shared__ float lh[2][NH], lR[2][NH], lse[2][NH];
    __shared__ float ps[16][NH];             // split-K partials
    __shared__ float hsumL[NH], shw2[NH];
    __shared__ float lagg[2][NH];
    __shared__ float lgp[2][2][512];         // [khalf][row][gatecol]

    // (1) own-row state loads + hsum partials (8 rows per group).
    if (tid < 256) {
        int rr = tid >> 7, k = tid & 127;
        lh[rr][k]  = hcur[(r0 + rr) * NH + k];
        lR[rr][k]  = p.R [(r0 + rr) * NH + k];
        lse[rr][k] = p.se[(r0 + rr) * NH + k];
    }
    if (t > 0) {
        float s = 0.f;
        const float* hb = hcur + (b * NA + g8 * 8) * NH + n;
#pragma unroll
        for (int j = 0; j < 8; ++j) s += hb[j * NH];
        ps[g8][n] = s;
    }
    __syncthreads();
    // (2) hsum combine.
    if (t > 0 && tid < NH) {
        float s = 0.f;
#pragma unroll
        for (int q = 0; q < 8; ++q) s += ps[q][tid];
        hsumL[tid] = s;
    }
    __syncthreads();
    // (3) shw2 = hsum @ W2, split K=128 into 8x16.
    if (t > 0) {
        float s = 0.f;
        const float* w2 = p.W_edge + NH * NH + n;
#pragma unroll
        for (int k = 16 * g8; k < 16 * g8 + 16; ++k) s += hsumL[k] * w2[k * NH];
        ps[g8][n] = s;
    }
    __syncthreads();
    if (tid < NH) {
        float s = 0.f;
        if (t > 0) {
#pragma unroll
            for (int q = 0; q < 8; ++q) s += ps[q][tid];
        }
        shw2[tid] = s;
    }
    __syncthreads();

    // Stage A: 4 paths x 2 K-halves; each group computes both rows.
    {
        const int path = g8 >> 1, kh = g8 & 1;
        const float* wb; const float* d0; const float* d1;
        if (path == 0)      { wb = p.W_edge + n;               d0 = lh[0];  d1 = lh[1];  }
        else if (path == 1) { wb = p.W_edge + 2 * NH * NH + n; d0 = lR[0];  d1 = lR[1];  }
        else if (path == 2) { wb = p.W_self + n;               d0 = lh[0];  d1 = lh[1];  }
        else                { wb = p.W_self + NH * NH + n;     d0 = lse[0]; d1 = lse[1]; }
        float a0 = 0.f, a1 = 0.f;
#pragma unroll 8
        for (int k = 64 * kh; k < 64 * kh + 64; ++k) {
            float w = wb[k * NH];
            a0 += d0[k] * w; a1 += d1[k] * w;
        }
        ps[g8 * 2 + 0][n] = a0;
        ps[g8 * 2 + 1][n] = a1;
    }
    __syncthreads();
    // Combine: R_new, se_new, agg.
    if (tid < 256) {
        int rr = tid >> 7, k = tid & 127;
        float a1v = ps[0 + rr][k] + ps[2 + rr][k];       // path0 (h@W1)
        float a3v = ps[4 + rr][k] + ps[6 + rr][k];       // path1 (R@W3)
        float aSv = ps[8 + rr][k] + ps[10 + rr][k]       // path2 (h@Ws1)
                  + ps[12 + rr][k] + ps[14 + rr][k];     // path3 (se@Ws2)
        float Rn = 64.f * a1v + shw2[k] + a3v + 64.f * p.b_edge[k];
        float Sn = aSv + p.sesty[(r0 + rr) * NH + k];
        p.R [(r0 + rr) * NH + k] = Rn;
        p.se[(r0 + rr) * NH + k] = Sn;
        lagg[rr][k] = Rn + Sn;
    }
    __syncthreads();

    // Stage C: gates; 512 cols x 2 K-halves, both rows per thread.
    {
        const int c = tid & 511, kh2 = tid >> 9;
        float a0 = 0.f, a1v = 0.f;
        if (kh2 == 0) {
            a0  = p.Xs[((size_t)r0 * NT + t) * 512 + c];
            a1v = p.Xs[((size_t)(r0 + 1) * NT + t) * 512 + c];
        }
        if (t > 0) {
            const float* wc = p.Wcomb + c;
            const float* wh = p.W_hh + c;
#pragma unroll 8
            for (int k = 64 * kh2; k < 64 * kh2 + 64; ++k) {
                float w = wc[k * 512];
                a0 += lagg[0][k] * w; a1v += lagg[1][k] * w;
            }
#pragma unroll 8
            for (int k = 64 * kh2; k < 64 * kh2 + 64; ++k) {
                float w = wh[k * 512];
                a0 += lh[0][k] * w; a1v += lh[1][k] * w;
            }
        }
        lgp[kh2][0][c] = a0;
        lgp[kh2][1][c] = a1v;
    }
    __syncthreads();

    // Stage D: combine K-halves + LSTM elementwise; publish h.
    if (tid < 256) {
        const int rr = tid >> 7, k = tid & 127, g = r0 + rr;
        float gi = lgp[0][rr][k]          + lgp[1][rr][k];
        float gf = lgp[0][rr][NH + k]     + lgp[1][rr][NH + k];
        float gg = lgp[0][rr][2 * NH + k] + lgp[1][rr][2 * NH + k];
        float go = lgp[0][rr][3 * NH + k] + lgp[1][rr][3 * NH + k];
        float si = 1.f / (1.f + expf(-gi));
        float sf = 1.f / (1.f + expf(-gf));
        float so = 1.f / (1.f + expf(-go));
        float cn = sf * p.c[g * NH + k] + si * tanhf(gg);
        float hn = so * tanhf(cn);
        p.c[g * NH + k] = cn;
        hnxt[g * NH + k] = hn;
        p.hall[((size_t)g * NT + t) * NH + k] = hn;
    }
}

// ---- Output projection over all (g,t) ----
__global__ void k_out(Params p) {
    const int row0 = blockIdx.x * 8, tid = threadIdx.x;
    __shared__ float lhL[8][NH];
    for (int idx = tid; idx < 8 * NH; idx += 256) {
        int r = idx >> 7, k = idx & 127;
        lhL[r][k] = p.hall[((size_t)(row0 + r)) * NH + k];
    }
    __syncthreads();
    const int n = tid & 127, half = tid >> 7, rb = half * 4;
    float a0 = p.b_pred[n], a1 = a0, a2 = a0, a3 = a0;
    for (int k = 0; k < NH; ++k) {
        float w = p.W_pred[k * NH + n];
        a0 += lhL[rb][k] * w; a1 += lhL[rb + 1][k] * w;
        a2 += lhL[rb + 2][k] * w; a3 += lhL[rb + 3][k] * w;
    }
    p.out[((size_t)(row0 + rb))     * NH + n] = fmaxf(a0, 0.f);
    p.out[((size_t)(row0 + rb + 1)) * NH + n] = fmaxf(a1, 0.f);
    p.out[((size_t)(row0 + rb + 2)) * NH + n] = fmaxf(a2, 0.f);
    p.out[((size_t)(row0 + rb + 3)) * NH + n] = fmaxf(a3, 0.f);
}

extern "C" void kernel_launch(void* const* d_in, const int* in_sizes, int n_in,
                              void* d_out, int out_size, void* d_ws, size_t ws_size,
                              hipStream_t stream) {
    const float* const* in = (const float* const*)d_in;
    Params p;
    p.traj = in[0]; p.ntraj = in[1]; p.ty = in[2]; p.sd = in[3]; p.adata = in[4]; p.rel = in[5];
    p.W_in = in[6]; p.b_in = in[7]; p.W_nt = in[8]; p.b_nt = in[9];
    p.W_ag = in[10]; p.b_ag = in[11]; p.W_sc = in[12]; p.b_sc = in[13];
    p.W_ein = in[14]; p.b_ein = in[15]; p.W_ety = in[16]; p.b_ety = in[17];
    p.W_edge = in[18]; p.b_edge = in[19]; p.W_self = in[20]; p.b_self = in[21];
    p.W_e2n = in[22]; p.b_e2n = in[23];
    p.W_ih = in[24]; p.W_hh = in[25]; p.b_ih = in[26]; p.b_hh = in[27];
    p.W_pred = in[28]; p.b_pred = in[29];

    float* ws = (float*)d_ws;
    const size_t S = (size_t)NB * NA * NH;   // 65536
    p.h0 = ws;                // zeroed
    p.h1 = ws + S;            // zeroed (written t=0 before read anyway)
    p.c  = ws + 2 * S;        // zeroed
    p.se = ws + 3 * S;        // zeroed
    p.R  = ws + 4 * S;        // k_r0
    float* w = ws + 5 * S;
    p.Wty   = w;              w += 8 * 512;
    p.Wsc   = w;              w += 32 * 512;
    p.Wag   = w;              w += 16 * 512;
    p.Wcomb = w;              w += 128 * 512;
    p.vbase = w;              w += 512;
    p.vag   = w;              w += 512;
    p.vbe   = w;              w += 512;
    p.sesty = w;              w += (size_t)NB * NA * NH;
    p.Xs    = w;              w += (size_t)NB * NA * NT * 512;
    p.hall  = w;              w += (size_t)NB * NA * NT * NH;
    p.out = (float*)d_out;

    hipMemsetAsync(p.h0, 0, 4 * S * sizeof(float), stream);   // h0,h1,c,se
    k_fold<<<185, 512, 0, stream>>>(p);
    k_r0<<<NB * NA, 128, 0, stream>>>(p);
    k_xstatic<<<NB * NA, 512, 0, stream>>>(p);
    for (int t = 0; t < NT; ++t)
        k_step<<<NB * NA / 2, 1024, 0, stream>>>(p, t);
    k_out<<<NB * NA * NT / 8, 256, 0, stream>>>(p);
}